// Round 3
// baseline (236.618 us; speedup 1.0000x reference)
//
#include <hip/hip_runtime.h>
#include <cstddef>
#include <cstdint>

// x (16,4096,256) fp32, kernels (512,256) fp32, out (16,4096,256) fp32
#define BSZ 16
#define PN  4096
#define DD  256
#define CC  512
#define TP  128          // positions per block
#define TC  64           // channels per block
#define NPT (PN / TP)    // 32 position tiles
#define NCT (CC / TC)    // 8 channel tiles
#define NKC 8            // 8 K-chunks of 32

typedef short bf16x8 __attribute__((ext_vector_type(8)));
typedef float f32x4  __attribute__((ext_vector_type(4)));

#define MEMFENCE() __asm__ __volatile__("" ::: "memory")
// s_waitcnt imm: vmcnt[3:0]=bits3:0, expcnt=bits6:4, lgkmcnt=bits12:8, vmcnt[5:4]=bits15:14
#define WAITCNT_VM0 0x1F70

struct Top2 { float v1, v2; int i1, i2; };

// larger value wins; tie -> smaller index (jnp.argmax first-occurrence)
__device__ __forceinline__ void t2_insert(Top2& t, float v, int i) {
  if (v > t.v1 || (v == t.v1 && i < t.i1)) {
    t.v2 = t.v1; t.i2 = t.i1; t.v1 = v; t.i1 = i;
  } else if (v > t.v2 || (v == t.v2 && i < t.i2)) {
    t.v2 = v; t.i2 = i;
  }
}

// split float4 -> packed bf16 hi (truncate) + bf16 lo (truncate of exact residual)
__device__ __forceinline__ void split4(float4 v, uint2& hp, uint2& lp) {
  uint32_t u0 = __float_as_uint(v.x), u1 = __float_as_uint(v.y),
           u2 = __float_as_uint(v.z), u3 = __float_as_uint(v.w);
  float l0 = v.x - __uint_as_float(u0 & 0xffff0000u);
  float l1 = v.y - __uint_as_float(u1 & 0xffff0000u);
  float l2 = v.z - __uint_as_float(u2 & 0xffff0000u);
  float l3 = v.w - __uint_as_float(u3 & 0xffff0000u);
  hp.x = __builtin_amdgcn_perm(u1, u0, 0x07060302u);
  hp.y = __builtin_amdgcn_perm(u3, u2, 0x07060302u);
  lp.x = __builtin_amdgcn_perm(__float_as_uint(l1), __float_as_uint(l0), 0x07060302u);
  lp.y = __builtin_amdgcn_perm(__float_as_uint(l3), __float_as_uint(l2), 0x07060302u);
}

// async 16B global -> LDS (dest = wave-uniform base + lane*16; global addr per-lane)
__device__ __forceinline__ void gld16(const void* gsrc, void* ldst) {
  __builtin_amdgcn_global_load_lds(
      (const __attribute__((address_space(1))) unsigned int*)gsrc,
      (__attribute__((address_space(3))) unsigned int*)ldst, 16, 0, 0);
}

// ---------------------------------------------------------------------------
// kernels (512x256) -> bf16 hi/lo in MFMA-staging slot order. UNCHANGED layout:
// chunk (ct128,kc) = 16 KB: hi[512 slots*16B] | lo[...]; slot s holds channel
// (s>>6)*16+(s&15) (within ct128 tile), k = kc*32 + ((s>>4)&3)*8 .. +8.
// ---------------------------------------------------------------------------
__global__ __launch_bounds__(256) void convert_k_kernel(
    const float* __restrict__ kern, uint32_t* __restrict__ ks) {
  const int kc = blockIdx.x, ct = blockIdx.y;   // ct over 128-wide tiles
  const size_t chunk = ((size_t)ct * NKC + kc) * 4096;
#pragma unroll
  for (int s0 = 0; s0 < 2; s0++) {
    int s  = threadIdx.x + s0 * 256;
    int fp = s >> 6, kg = (s >> 4) & 3, lr = s & 15;
    int r  = fp * 16 + lr, k0 = kg * 8;
    const float* src = kern + ((size_t)ct * 128 + r) * DD + kc * 32 + k0;
    float4 v0 = *(const float4*)src, v1 = *(const float4*)(src + 4);
    uint2 h0, l0, h1, l1; split4(v0, h0, l0); split4(v1, h1, l1);
    *(uint4*)&ks[chunk + (size_t)s * 4]        = make_uint4(h0.x, h0.y, h1.x, h1.y);
    *(uint4*)&ks[chunk + 2048 + (size_t)s * 4] = make_uint4(l0.x, l0.y, l1.x, l1.y);
  }
}

// ---------------------------------------------------------------------------
// Score GEMM v3: 128p x 64c per block, 4 waves x (32p x 64c).
// B (all 8 K-chunks, 64 KB) staged to LDS ONCE via gld16 -> single barrier.
// A is per-wave private: loaded global->registers, 1-chunk-ahead pipeline,
// fully unrolled K-loop (static reg-buffer indices), NO in-loop barriers.
// Split-bf16 3-MFMA numerics identical to previous version (absmax 0.0).
// ---------------------------------------------------------------------------
__global__ __launch_bounds__(256, 2) void score_kernel(
    const float* __restrict__ x, const uint32_t* __restrict__ ks,
    float2* __restrict__ pv2, uint32_t* __restrict__ pix) {

  __shared__ __align__(16) char lds[65536];
  // B layout: [kc][h][fc*1024 + lane*16]  -> byte = kc*8192 + h*4096 + fc*1024 + l*16

  // nwg = 4096; hw round-robins blockIdx % 8 over XCDs; ct cycles fastest
  // in time on each XCD so the 8 ct-blocks of an x-tile share one L2.
  const int d  = blockIdx.x;
  const int L  = (d & 7) * 512 + (d >> 3);   // bijective (4096 % 8 == 0)
  const int ct = L & 7;
  const int pt = (L >> 3) & 31;
  const int b  = L >> 8;

  const int tid = threadIdx.x;
  const int lane = tid & 63, w = tid >> 6;
  const int lr = lane & 15, kg = lane >> 4;

  // ---- stage ALL B chunks (64 KB) ----
  const char* ksbase = (const char*)ks + (size_t)(ct >> 1) * NKC * 16384 + (ct & 1) * 4096;
#pragma unroll
  for (int kc = 0; kc < NKC; kc++) {
#pragma unroll
    for (int h = 0; h < 2; h++)
      gld16(ksbase + kc * 16384 + h * 8192 + tid * 16,
            lds + kc * 8192 + h * 4096 + tid * 16);
  }

  // ---- A pointers: row = w*32 + fp*16 + lr, k elems = kc*32 + kg*8 + h*4 ----
  const char* xbase = (const char*)(x + ((size_t)b * PN + (size_t)pt * TP) * DD);
  const char* ap[2][2];
#pragma unroll
  for (int fp = 0; fp < 2; fp++)
#pragma unroll
    for (int h = 0; h < 2; h++)
      ap[fp][h] = xbase + (size_t)(w * 32 + fp * 16 + lr) * (DD * 4) + kg * 32 + h * 16;

  float4 abuf[2][2][2];   // [kc&1][fp][h] -- all indices compile-time (full unroll)
  auto loadA = [&](int kc) {
#pragma unroll
    for (int fp = 0; fp < 2; fp++)
#pragma unroll
      for (int h = 0; h < 2; h++)
        abuf[kc & 1][fp][h] = *(const float4*)(ap[fp][h] + kc * 128);
  };

  loadA(0);
  MEMFENCE();
  __builtin_amdgcn_s_waitcnt(WAITCNT_VM0);   // B staged + A0 landed
  __builtin_amdgcn_s_barrier();
  MEMFENCE();

  f32x4 acc[2][4];
#pragma unroll
  for (int i = 0; i < 2; i++)
#pragma unroll
    for (int j = 0; j < 4; j++) acc[i][j] = (f32x4)0.f;

#pragma unroll
  for (int kc = 0; kc < NKC; kc++) {
    if (kc + 1 < NKC) loadA(kc + 1);         // 1-deep per-wave prefetch

    bf16x8 Ah[2], Al[2];
#pragma unroll
    for (int fp = 0; fp < 2; fp++) {
      uint2 h0, l0, h1, l1;
      split4(abuf[kc & 1][fp][0], h0, l0);
      split4(abuf[kc & 1][fp][1], h1, l1);
      uint4 hh = make_uint4(h0.x, h0.y, h1.x, h1.y);
      uint4 ll = make_uint4(l0.x, l0.y, l1.x, l1.y);
      Ah[fp] = *(bf16x8*)&hh;
      Al[fp] = *(bf16x8*)&ll;
    }
#pragma unroll
    for (int fc = 0; fc < 4; fc++) {
      bf16x8 Bh = *(const bf16x8*)(lds + kc * 8192 + fc * 1024 + lane * 16);
      bf16x8 Bl = *(const bf16x8*)(lds + kc * 8192 + 4096 + fc * 1024 + lane * 16);
#pragma unroll
      for (int fp = 0; fp < 2; fp++) {
        acc[fp][fc] = __builtin_amdgcn_mfma_f32_16x16x32_bf16(Ah[fp], Bh, acc[fp][fc], 0, 0, 0);
        acc[fp][fc] = __builtin_amdgcn_mfma_f32_16x16x32_bf16(Ah[fp], Bl, acc[fp][fc], 0, 0, 0);
        acc[fp][fc] = __builtin_amdgcn_mfma_f32_16x16x32_bf16(Al[fp], Bh, acc[fp][fc], 0, 0, 0);
      }
    }
  }

  __syncthreads();                           // all waves done reading LDS B

  // relu + per-lane top2 per column (C layout: col=lane&15, row=(lane>>4)*4+reg)
  float4* scratch = (float4*)lds;            // reuse B region: [slot 0..15][col 0..63]
  const int slot = w * 4 + kg;
#pragma unroll
  for (int fc = 0; fc < 4; fc++) {
    Top2 t; t.v1 = -1.f; t.v2 = -1.f; t.i1 = 0x7fffffff; t.i2 = 0x7fffffff;
#pragma unroll
    for (int fp = 0; fp < 2; fp++)
#pragma unroll
      for (int r = 0; r < 4; r++) {
        float v = acc[fp][fc][r]; v = v > 0.f ? v : 0.f;
        t2_insert(t, v, w * 32 + fp * 16 + kg * 4 + r);
      }
    scratch[slot * TC + fc * 16 + lr] =
        make_float4(t.v1, __int_as_float(t.i1), t.v2, __int_as_float(t.i2));
  }
  __syncthreads();

  if (tid < TC) {
    Top2 t; t.v1 = -1.f; t.v2 = -1.f; t.i1 = 0x7fffffff; t.i2 = 0x7fffffff;
#pragma unroll
    for (int s = 0; s < 16; s++) {
      float4 e = scratch[s * TC + tid];
      t2_insert(t, e.x, __float_as_int(e.y));
      t2_insert(t, e.z, __float_as_int(e.w));
    }
    int c = ct * TC + tid;
    size_t o = ((size_t)b * CC + c) * NPT + pt;
    uint32_t p1 = (uint32_t)(pt * TP + t.i1);
    uint32_t p2 = (uint32_t)(pt * TP + t.i2);
    pv2[o] = make_float2(t.v1, t.v2);
    pix[o] = (p1 << 16) | (p2 & 0xffffu);
  }
}

// ---------------------------------------------------------------------------
// Per-(b,c): merge 32 tile top-2s; eps-guarded winner; exact fp32 rescue of
// near-ties. Writes winner[b][c] only.
// ---------------------------------------------------------------------------
__global__ __launch_bounds__(64) void reduce_winner_kernel(
    const float2* __restrict__ pv2, const uint32_t* __restrict__ pix,
    const float* __restrict__ x, const float* __restrict__ kern,
    int* __restrict__ winner) {
  const int c = blockIdx.x, b = blockIdx.y;
  const int l = threadIdx.x;

  Top2 t; t.v1 = -1.f; t.v2 = -1.f; t.i1 = 0x7fffffff; t.i2 = 0x7fffffff;
  if (l < NPT) {
    size_t o = ((size_t)b * CC + c) * NPT + l;
    float2 v = pv2[o]; uint32_t ii = pix[o];
    t.v1 = v.x; t.v2 = v.y; t.i1 = (int)(ii >> 16); t.i2 = (int)(ii & 0xffffu);
  }
#pragma unroll
  for (int m = 1; m < 64; m <<= 1) {
    float uv1 = __shfl_xor(t.v1, m, 64);
    int   ui1 = __shfl_xor(t.i1, m, 64);
    float uv2 = __shfl_xor(t.v2, m, 64);
    int   ui2 = __shfl_xor(t.i2, m, 64);
    t2_insert(t, uv1, ui1);
    t2_insert(t, uv2, ui2);
  }

  int win = t.i1;
  if (t.v1 - t.v2 <= 1e-4f * t.v1 + 1e-5f) {   // rare near-tie: exact fp32
    const float4* x1 = (const float4*)(x + ((size_t)b * PN + t.i1) * DD);
    const float4* x2 = (const float4*)(x + ((size_t)b * PN + t.i2) * DD);
    const float4* kc = (const float4*)(kern + (size_t)c * DD);
    float4 a1 = x1[l], a2 = x2[l], k4 = kc[l];
    float s1 = a1.x * k4.x + a1.y * k4.y + a1.z * k4.z + a1.w * k4.w;
    float s2 = a2.x * k4.x + a2.y * k4.y + a2.z * k4.z + a2.w * k4.w;
#pragma unroll
    for (int m = 1; m < 64; m <<= 1) {
      s1 += __shfl_xor(s1, m, 64);
      s2 += __shfl_xor(s2, m, 64);
    }
    s1 = fmaxf(s1, 0.f); s2 = fmaxf(s2, 0.f);
    if (s2 > s1 || (s2 == s1 && t.i2 < t.i1)) win = t.i2;
  }
  if (l == 0) winner[(size_t)b * CC + c] = win;
}

// ---------------------------------------------------------------------------
// 4 positions per block (4 waves); winner row staged in LDS once per block.
// Each wave ballots matching channels, sums kernel rows, writes its row.
// Full coverage -> no memset, no atomics.
// ---------------------------------------------------------------------------
__global__ __launch_bounds__(256) void write_out_kernel(
    const int* __restrict__ winner, const float* __restrict__ kern,
    float4* __restrict__ out) {
  __shared__ __align__(16) int wrow[CC];
  const int b = blockIdx.y;
  const int tid = threadIdx.x, lane = tid & 63, w = tid >> 6;
  const int p = blockIdx.x * 4 + w;

  *(int2*)&wrow[tid * 2] = *(const int2*)&winner[(size_t)b * CC + tid * 2];
  __syncthreads();

  int4 w0 = *(const int4*)&wrow[lane * 8];
  int4 w1 = *(const int4*)&wrow[lane * 8 + 4];
  int wv[8] = {w0.x, w0.y, w0.z, w0.w, w1.x, w1.y, w1.z, w1.w};

  float4 acc = make_float4(0.f, 0.f, 0.f, 0.f);
#pragma unroll
  for (int j = 0; j < 8; j++) {
    unsigned long long m = __ballot(wv[j] == p);
    while (m) {
      int bit = __ffsll((long long)m) - 1; m &= m - 1;
      int c = bit * 8 + j;                      // wave-uniform
      float4 kv = ((const float4*)(kern + (size_t)c * DD))[lane];
      acc.x += kv.x; acc.y += kv.y; acc.z += kv.z; acc.w += kv.w;
    }
  }
  out[((size_t)b * PN + p) * 64 + lane] = acc;
}

// ---------------------------------------------------------------------------
extern "C" void kernel_launch(void* const* d_in, const int* in_sizes, int n_in,
                              void* d_out, int out_size, void* d_ws, size_t ws_size,
                              hipStream_t stream) {
  const float* x    = (const float*)d_in[0];   // (16,4096,256)
  const float* kern = (const float*)d_in[1];   // (512,256)
  float* out = (float*)d_out;

  // ws: pv2 2 MB | pix 1 MB | ks 512 KB | winner 32 KB
  char* ws = (char*)d_ws;
  float2*   pv2 = (float2*)ws;
  uint32_t* pix = (uint32_t*)(ws + (size_t)BSZ * CC * NPT * sizeof(float2));
  uint32_t* ks  = (uint32_t*)(ws + 3u * 1024 * 1024);
  int*      win = (int*)(ws + 3u * 1024 * 1024 + 512u * 1024);

  convert_k_kernel<<<dim3(NKC, CC / 128), 256, 0, stream>>>(kern, ks);

  score_kernel<<<dim3(NCT * NPT * BSZ), 256, 0, stream>>>(x, ks, pv2, pix);

  reduce_winner_kernel<<<dim3(CC, BSZ), 64, 0, stream>>>(pv2, pix, x, kern, win);

  write_out_kernel<<<dim3(PN / 4, BSZ), 256, 0, stream>>>(win, kern, (float4*)out);
}

// Round 4
// 196.180 us; speedup vs baseline: 1.2061x; 1.2061x over previous
//
#include <hip/hip_runtime.h>
#include <cstddef>
#include <cstdint>

// x (16,4096,256) fp32, kernels (512,256) fp32, out (16,4096,256) fp32
#define BSZ 16
#define PN  4096
#define DD  256
#define CC  512
#define TP  128          // positions per block
#define TC  64           // channels per block
#define NPT (PN / TP)    // 32 position tiles
#define NCT (CC / TC)    // 8 channel tiles
#define NKC 8            // 8 K-chunks of 32

typedef short bf16x8 __attribute__((ext_vector_type(8)));
typedef float f32x4  __attribute__((ext_vector_type(4)));

#define MEMFENCE() __asm__ __volatile__("" ::: "memory")
// s_waitcnt imm: vmcnt[3:0]=bits3:0, expcnt=bits6:4, lgkmcnt=bits12:8, vmcnt[5:4]=bits15:14
#define WAITCNT_VM0 0x1F70

struct Top2 { float v1, v2; int i1, i2; };

// larger value wins; tie -> smaller index (jnp.argmax first-occurrence)
__device__ __forceinline__ void t2_insert(Top2& t, float v, int i) {
  if (v > t.v1 || (v == t.v1 && i < t.i1)) {
    t.v2 = t.v1; t.i2 = t.i1; t.v1 = v; t.i1 = i;
  } else if (v > t.v2 || (v == t.v2 && i < t.i2)) {
    t.v2 = v; t.i2 = i;
  }
}

// split float4 -> packed bf16 hi (truncate) + bf16 lo (truncate of exact residual)
__device__ __forceinline__ void split4(float4 v, uint2& hp, uint2& lp) {
  uint32_t u0 = __float_as_uint(v.x), u1 = __float_as_uint(v.y),
           u2 = __float_as_uint(v.z), u3 = __float_as_uint(v.w);
  float l0 = v.x - __uint_as_float(u0 & 0xffff0000u);
  float l1 = v.y - __uint_as_float(u1 & 0xffff0000u);
  float l2 = v.z - __uint_as_float(u2 & 0xffff0000u);
  float l3 = v.w - __uint_as_float(u3 & 0xffff0000u);
  hp.x = __builtin_amdgcn_perm(u1, u0, 0x07060302u);
  hp.y = __builtin_amdgcn_perm(u3, u2, 0x07060302u);
  lp.x = __builtin_amdgcn_perm(__float_as_uint(l1), __float_as_uint(l0), 0x07060302u);
  lp.y = __builtin_amdgcn_perm(__float_as_uint(l3), __float_as_uint(l2), 0x07060302u);
}

// async 16B global -> LDS (dest = wave-uniform base + lane*16; global addr per-lane)
__device__ __forceinline__ void gld16(const void* gsrc, void* ldst) {
  __builtin_amdgcn_global_load_lds(
      (const __attribute__((address_space(1))) unsigned int*)gsrc,
      (__attribute__((address_space(3))) unsigned int*)ldst, 16, 0, 0);
}

// ---------------------------------------------------------------------------
// kernels (512x256) -> bf16 hi/lo in MFMA-staging slot order. UNCHANGED layout:
// chunk (ct128,kc) = 16 KB: hi[512 slots*16B] | lo[...]; slot s holds channel
// (s>>6)*16+(s&15) (within ct128 tile), k = kc*32 + ((s>>4)&3)*8 .. +8.
// ---------------------------------------------------------------------------
__global__ __launch_bounds__(256) void convert_k_kernel(
    const float* __restrict__ kern, uint32_t* __restrict__ ks) {
  const int kc = blockIdx.x, ct = blockIdx.y;   // ct over 128-wide tiles
  const size_t chunk = ((size_t)ct * NKC + kc) * 4096;
#pragma unroll
  for (int s0 = 0; s0 < 2; s0++) {
    int s  = threadIdx.x + s0 * 256;
    int fp = s >> 6, kg = (s >> 4) & 3, lr = s & 15;
    int r  = fp * 16 + lr, k0 = kg * 8;
    const float* src = kern + ((size_t)ct * 128 + r) * DD + kc * 32 + k0;
    float4 v0 = *(const float4*)src, v1 = *(const float4*)(src + 4);
    uint2 h0, l0, h1, l1; split4(v0, h0, l0); split4(v1, h1, l1);
    *(uint4*)&ks[chunk + (size_t)s * 4]        = make_uint4(h0.x, h0.y, h1.x, h1.y);
    *(uint4*)&ks[chunk + 2048 + (size_t)s * 4] = make_uint4(l0.x, l0.y, l1.x, l1.y);
  }
}

// ---------------------------------------------------------------------------
// Score GEMM v4: 128p x 64c per block, 4 waves x (32p x 64c).
// Round-2 per-chunk schedule (issue prefetch -> compute -> vmcnt(0) -> barrier)
// but A goes global->registers (no A LDS, no A ds_reads). B double-buffered in
// 16 KB LDS via gld16. LDS 16 KB + VGPR<=128 -> 4 blocks/CU (50% occ cap).
// Split-bf16 3-MFMA numerics identical to all passing versions (absmax 0.0).
// ---------------------------------------------------------------------------
__global__ __launch_bounds__(256, 4) void score_kernel(
    const float* __restrict__ x, const uint32_t* __restrict__ ks,
    float2* __restrict__ pv2, uint32_t* __restrict__ pix) {

  __shared__ __align__(16) char lds[16384];
  // B0 [0,8K) | B1 [8K,16K); each: [h][fc*1024 + lane*16]
  // epilogue reuses [0,16K) as top-2 scratch (after loop-end barrier).

  // nwg = 4096; hw round-robins blockIdx % 8 over XCDs; ct cycles fastest
  // in time on each XCD so the 8 ct-blocks of an x-tile share one L2.
  const int d  = blockIdx.x;
  const int L  = (d & 7) * 512 + (d >> 3);   // bijective (4096 % 8 == 0)
  const int ct = L & 7;
  const int pt = (L >> 3) & 31;
  const int b  = L >> 8;

  const int tid = threadIdx.x;
  const int lane = tid & 63, w = tid >> 6;
  const int lr = lane & 15, kg = lane >> 4;

  // ---- B staging addresses (same mapping as r2, which passed) ----
  const char* ksbase = (const char*)ks + (size_t)(ct >> 1) * NKC * 16384 + (ct & 1) * 4096;
  const char* bsrc[2];
  bsrc[0] = ksbase + tid * 16;          // hi half-chunk quarter
  bsrc[1] = ksbase + 8192 + tid * 16;   // lo

  // ---- A pointers: row = w*32 + fp*16 + lr, k elems = kc*32 + kg*8 + h*4 ----
  const char* xbase = (const char*)(x + ((size_t)b * PN + (size_t)pt * TP) * DD);
  const char* ap[2][2];
#pragma unroll
  for (int fp = 0; fp < 2; fp++)
#pragma unroll
    for (int h = 0; h < 2; h++)
      ap[fp][h] = xbase + (size_t)(w * 32 + fp * 16 + lr) * (DD * 4) + kg * 32 + h * 16;

  float4 abuf[2][2][2];   // [kc&1][fp][h] -- all indices compile-time (full unroll)

  auto issue = [&](int kc) {
    // B -> LDS (2 gld16/thread)
    char* Bb = lds + (kc & 1) * 8192;
#pragma unroll
    for (int i = 0; i < 2; i++)
      gld16(bsrc[i] + kc * 16384, Bb + i * 4096 + tid * 16);
    // A -> regs (4 loads/thread)
#pragma unroll
    for (int fp = 0; fp < 2; fp++)
#pragma unroll
      for (int h = 0; h < 2; h++)
        abuf[kc & 1][fp][h] = *(const float4*)(ap[fp][h] + kc * 128);
  };

  issue(0);
  MEMFENCE();
  __builtin_amdgcn_s_waitcnt(WAITCNT_VM0);   // chunk-0 A regs + B LDS landed
  __builtin_amdgcn_s_barrier();
  MEMFENCE();

  f32x4 acc[2][4];
#pragma unroll
  for (int i = 0; i < 2; i++)
#pragma unroll
    for (int j = 0; j < 4; j++) acc[i][j] = (f32x4)0.f;

#pragma unroll
  for (int kc = 0; kc < NKC; kc++) {
    if (kc + 1 < NKC) issue(kc + 1);         // in flight across this compute

    bf16x8 Ah[2], Al[2];
#pragma unroll
    for (int fp = 0; fp < 2; fp++) {
      uint2 h0, l0, h1, l1;
      split4(abuf[kc & 1][fp][0], h0, l0);
      split4(abuf[kc & 1][fp][1], h1, l1);
      uint4 hh = make_uint4(h0.x, h0.y, h1.x, h1.y);
      uint4 ll = make_uint4(l0.x, l0.y, l1.x, l1.y);
      Ah[fp] = *(bf16x8*)&hh;
      Al[fp] = *(bf16x8*)&ll;
    }
    const char* Bb = lds + (kc & 1) * 8192;
#pragma unroll
    for (int fc = 0; fc < 4; fc++) {
      bf16x8 Bh = *(const bf16x8*)(Bb + fc * 1024 + lane * 16);
      bf16x8 Bl = *(const bf16x8*)(Bb + 4096 + fc * 1024 + lane * 16);
#pragma unroll
      for (int fp = 0; fp < 2; fp++) {
        acc[fp][fc] = __builtin_amdgcn_mfma_f32_16x16x32_bf16(Ah[fp], Bh, acc[fp][fc], 0, 0, 0);
        acc[fp][fc] = __builtin_amdgcn_mfma_f32_16x16x32_bf16(Ah[fp], Bl, acc[fp][fc], 0, 0, 0);
        acc[fp][fc] = __builtin_amdgcn_mfma_f32_16x16x32_bf16(Al[fp], Bh, acc[fp][fc], 0, 0, 0);
      }
    }
    MEMFENCE();
    __builtin_amdgcn_s_waitcnt(WAITCNT_VM0); // next-chunk A+B landed
    __builtin_amdgcn_s_barrier();            // all waves' reads of victim buf done
    MEMFENCE();
  }
  // loop-end barrier doubles as pre-scratch sync (all chunk-7 LDS reads retired)

  // relu + per-lane top2 per column (C layout: col=lane&15, row=(lane>>4)*4+reg)
  float4* scratch = (float4*)lds;            // [slot 0..15][col 0..63] = 16 KB
  const int slot = w * 4 + kg;
#pragma unroll
  for (int fc = 0; fc < 4; fc++) {
    Top2 t; t.v1 = -1.f; t.v2 = -1.f; t.i1 = 0x7fffffff; t.i2 = 0x7fffffff;
#pragma unroll
    for (int fp = 0; fp < 2; fp++)
#pragma unroll
      for (int r = 0; r < 4; r++) {
        float v = acc[fp][fc][r]; v = v > 0.f ? v : 0.f;
        t2_insert(t, v, w * 32 + fp * 16 + kg * 4 + r);
      }
    scratch[slot * TC + fc * 16 + lr] =
        make_float4(t.v1, __int_as_float(t.i1), t.v2, __int_as_float(t.i2));
  }
  __syncthreads();

  if (tid < TC) {
    Top2 t; t.v1 = -1.f; t.v2 = -1.f; t.i1 = 0x7fffffff; t.i2 = 0x7fffffff;
#pragma unroll
    for (int s = 0; s < 16; s++) {
      float4 e = scratch[s * TC + tid];
      t2_insert(t, e.x, __float_as_int(e.y));
      t2_insert(t, e.z, __float_as_int(e.w));
    }
    int c = ct * TC + tid;
    size_t o = ((size_t)b * CC + c) * NPT + pt;
    uint32_t p1 = (uint32_t)(pt * TP + t.i1);
    uint32_t p2 = (uint32_t)(pt * TP + t.i2);
    pv2[o] = make_float2(t.v1, t.v2);
    pix[o] = (p1 << 16) | (p2 & 0xffffu);
  }
}

// ---------------------------------------------------------------------------
// Per-(b,c): merge 32 tile top-2s; eps-guarded winner; exact fp32 rescue of
// near-ties. Writes winner[b][c] only.
// ---------------------------------------------------------------------------
__global__ __launch_bounds__(64) void reduce_winner_kernel(
    const float2* __restrict__ pv2, const uint32_t* __restrict__ pix,
    const float* __restrict__ x, const float* __restrict__ kern,
    int* __restrict__ winner) {
  const int c = blockIdx.x, b = blockIdx.y;
  const int l = threadIdx.x;

  Top2 t; t.v1 = -1.f; t.v2 = -1.f; t.i1 = 0x7fffffff; t.i2 = 0x7fffffff;
  if (l < NPT) {
    size_t o = ((size_t)b * CC + c) * NPT + l;
    float2 v = pv2[o]; uint32_t ii = pix[o];
    t.v1 = v.x; t.v2 = v.y; t.i1 = (int)(ii >> 16); t.i2 = (int)(ii & 0xffffu);
  }
#pragma unroll
  for (int m = 1; m < 64; m <<= 1) {
    float uv1 = __shfl_xor(t.v1, m, 64);
    int   ui1 = __shfl_xor(t.i1, m, 64);
    float uv2 = __shfl_xor(t.v2, m, 64);
    int   ui2 = __shfl_xor(t.i2, m, 64);
    t2_insert(t, uv1, ui1);
    t2_insert(t, uv2, ui2);
  }

  int win = t.i1;
  if (t.v1 - t.v2 <= 1e-4f * t.v1 + 1e-5f) {   // rare near-tie: exact fp32
    const float4* x1 = (const float4*)(x + ((size_t)b * PN + t.i1) * DD);
    const float4* x2 = (const float4*)(x + ((size_t)b * PN + t.i2) * DD);
    const float4* kc = (const float4*)(kern + (size_t)c * DD);
    float4 a1 = x1[l], a2 = x2[l], k4 = kc[l];
    float s1 = a1.x * k4.x + a1.y * k4.y + a1.z * k4.z + a1.w * k4.w;
    float s2 = a2.x * k4.x + a2.y * k4.y + a2.z * k4.z + a2.w * k4.w;
#pragma unroll
    for (int m = 1; m < 64; m <<= 1) {
      s1 += __shfl_xor(s1, m, 64);
      s2 += __shfl_xor(s2, m, 64);
    }
    s1 = fmaxf(s1, 0.f); s2 = fmaxf(s2, 0.f);
    if (s2 > s1 || (s2 == s1 && t.i2 < t.i1)) win = t.i2;
  }
  if (l == 0) winner[(size_t)b * CC + c] = win;
}

// ---------------------------------------------------------------------------
// 4 positions per block (4 waves); winner row staged in LDS once per block.
// Each wave ballots matching channels, sums kernel rows, writes its row.
// Full coverage -> no memset, no atomics.
// ---------------------------------------------------------------------------
__global__ __launch_bounds__(256) void write_out_kernel(
    const int* __restrict__ winner, const float* __restrict__ kern,
    float4* __restrict__ out) {
  __shared__ __align__(16) int wrow[CC];
  const int b = blockIdx.y;
  const int tid = threadIdx.x, lane = tid & 63, w = tid >> 6;
  const int p = blockIdx.x * 4 + w;

  *(int2*)&wrow[tid * 2] = *(const int2*)&winner[(size_t)b * CC + tid * 2];
  __syncthreads();

  int4 w0 = *(const int4*)&wrow[lane * 8];
  int4 w1 = *(const int4*)&wrow[lane * 8 + 4];
  int wv[8] = {w0.x, w0.y, w0.z, w0.w, w1.x, w1.y, w1.z, w1.w};

  float4 acc = make_float4(0.f, 0.f, 0.f, 0.f);
#pragma unroll
  for (int j = 0; j < 8; j++) {
    unsigned long long m = __ballot(wv[j] == p);
    while (m) {
      int bit = __ffsll((long long)m) - 1; m &= m - 1;
      int c = bit * 8 + j;                      // wave-uniform
      float4 kv = ((const float4*)(kern + (size_t)c * DD))[lane];
      acc.x += kv.x; acc.y += kv.y; acc.z += kv.z; acc.w += kv.w;
    }
  }
  out[((size_t)b * PN + p) * 64 + lane] = acc;
}

// ---------------------------------------------------------------------------
extern "C" void kernel_launch(void* const* d_in, const int* in_sizes, int n_in,
                              void* d_out, int out_size, void* d_ws, size_t ws_size,
                              hipStream_t stream) {
  const float* x    = (const float*)d_in[0];   // (16,4096,256)
  const float* kern = (const float*)d_in[1];   // (512,256)
  float* out = (float*)d_out;

  // ws: pv2 2 MB | pix 1 MB | ks 512 KB | winner 32 KB
  char* ws = (char*)d_ws;
  float2*   pv2 = (float2*)ws;
  uint32_t* pix = (uint32_t*)(ws + (size_t)BSZ * CC * NPT * sizeof(float2));
  uint32_t* ks  = (uint32_t*)(ws + 3u * 1024 * 1024);
  int*      win = (int*)(ws + 3u * 1024 * 1024 + 512u * 1024);

  convert_k_kernel<<<dim3(NKC, CC / 128), 256, 0, stream>>>(kern, ks);

  score_kernel<<<dim3(NCT * NPT * BSZ), 256, 0, stream>>>(x, ks, pv2, pix);

  reduce_winner_kernel<<<dim3(CC, BSZ), 64, 0, stream>>>(pv2, pix, x, kern, win);

  write_out_kernel<<<dim3(PN / 4, BSZ), 256, 0, stream>>>(win, kern, (float4*)out);
}

// Round 5
// 189.405 us; speedup vs baseline: 1.2493x; 1.0358x over previous
//
#include <hip/hip_runtime.h>
#include <cstddef>
#include <cstdint>

// x (16,4096,256) fp32, kernels (512,256) fp32, out (16,4096,256) fp32
#define BSZ 16
#define PN  4096
#define DD  256
#define CC  512
#define TP  128          // positions per block
#define TC  64           // channels per block
#define NPT (PN / TP)    // 32 position tiles
#define NCT (CC / TC)    // 8 channel tiles
#define NKC 8            // 8 K-chunks of 32

typedef short bf16x8 __attribute__((ext_vector_type(8)));
typedef float f32x4  __attribute__((ext_vector_type(4)));

#define MEMFENCE() __asm__ __volatile__("" ::: "memory")
// s_waitcnt imm: vmcnt[3:0]=bits3:0, expcnt=bits6:4, lgkmcnt=bits12:8, vmcnt[5:4]=bits15:14
#define WAITCNT_VM0 0x1F70
#define WAITCNT_VM6 0x1F76   // allow 6 VM ops (one issue-group) to stay in flight

struct Top2 { float v1, v2; int i1, i2; };

// larger value wins; tie -> smaller index (jnp.argmax first-occurrence)
__device__ __forceinline__ void t2_insert(Top2& t, float v, int i) {
  if (v > t.v1 || (v == t.v1 && i < t.i1)) {
    t.v2 = t.v1; t.i2 = t.i1; t.v1 = v; t.i1 = i;
  } else if (v > t.v2 || (v == t.v2 && i < t.i2)) {
    t.v2 = v; t.i2 = i;
  }
}

// split float4 -> packed bf16 hi (truncate) + bf16 lo (truncate of exact residual)
__device__ __forceinline__ void split4(float4 v, uint2& hp, uint2& lp) {
  uint32_t u0 = __float_as_uint(v.x), u1 = __float_as_uint(v.y),
           u2 = __float_as_uint(v.z), u3 = __float_as_uint(v.w);
  float l0 = v.x - __uint_as_float(u0 & 0xffff0000u);
  float l1 = v.y - __uint_as_float(u1 & 0xffff0000u);
  float l2 = v.z - __uint_as_float(u2 & 0xffff0000u);
  float l3 = v.w - __uint_as_float(u3 & 0xffff0000u);
  hp.x = __builtin_amdgcn_perm(u1, u0, 0x07060302u);
  hp.y = __builtin_amdgcn_perm(u3, u2, 0x07060302u);
  lp.x = __builtin_amdgcn_perm(__float_as_uint(l1), __float_as_uint(l0), 0x07060302u);
  lp.y = __builtin_amdgcn_perm(__float_as_uint(l3), __float_as_uint(l2), 0x07060302u);
}

// async 16B global -> LDS (dest = wave-uniform base + lane*16; global addr per-lane)
__device__ __forceinline__ void gld16(const void* gsrc, void* ldst) {
  __builtin_amdgcn_global_load_lds(
      (const __attribute__((address_space(1))) unsigned int*)gsrc,
      (__attribute__((address_space(3))) unsigned int*)ldst, 16, 0, 0);
}

// ---------------------------------------------------------------------------
// kernels (512x256) -> bf16 hi/lo in MFMA-staging slot order. UNCHANGED layout:
// chunk (ct128,kc) = 16 KB: hi[512 slots*16B] | lo[...]; slot s holds channel
// (s>>6)*16+(s&15) (within ct128 tile), k = kc*32 + ((s>>4)&3)*8 .. +8.
// ---------------------------------------------------------------------------
__global__ __launch_bounds__(256) void convert_k_kernel(
    const float* __restrict__ kern, uint32_t* __restrict__ ks) {
  const int kc = blockIdx.x, ct = blockIdx.y;   // ct over 128-wide tiles
  const size_t chunk = ((size_t)ct * NKC + kc) * 4096;
#pragma unroll
  for (int s0 = 0; s0 < 2; s0++) {
    int s  = threadIdx.x + s0 * 256;
    int fp = s >> 6, kg = (s >> 4) & 3, lr = s & 15;
    int r  = fp * 16 + lr, k0 = kg * 8;
    const float* src = kern + ((size_t)ct * 128 + r) * DD + kc * 32 + k0;
    float4 v0 = *(const float4*)src, v1 = *(const float4*)(src + 4);
    uint2 h0, l0, h1, l1; split4(v0, h0, l0); split4(v1, h1, l1);
    *(uint4*)&ks[chunk + (size_t)s * 4]        = make_uint4(h0.x, h0.y, h1.x, h1.y);
    *(uint4*)&ks[chunk + 2048 + (size_t)s * 4] = make_uint4(l0.x, l0.y, l1.x, l1.y);
  }
}

// ---------------------------------------------------------------------------
// Score GEMM v5: 128p x 64c per block, 4 waves x (32p x 64c).
// v4 schedule upgraded to a 2-deep counted-vmcnt pipeline (T4): B triple-
// buffered in 24 KB LDS, loads issued TWO chunks ahead, wait vmcnt(6) before
// each barrier so the newest issue-group (6 VM ops) stays in flight across it.
// A global->registers (abuf 3 parities, all indices compile-time).
// Split-bf16 3-MFMA numerics identical to all passing versions (absmax 0.0).
// ---------------------------------------------------------------------------
__global__ __launch_bounds__(256, 4) void score_kernel(
    const float* __restrict__ x, const uint32_t* __restrict__ ks,
    float2* __restrict__ pv2, uint32_t* __restrict__ pix) {

  __shared__ __align__(16) char lds[24576];
  // B0 [0,8K) | B1 [8K,16K) | B2 [16K,24K); each: [h][fc*1024 + lane*16]
  // epilogue reuses [0,16K) as top-2 scratch (after loop-end barrier).

  // nwg = 4096; hw round-robins blockIdx % 8 over XCDs; ct cycles fastest
  // in time on each XCD so the 8 ct-blocks of an x-tile share one L2.
  const int d  = blockIdx.x;
  const int L  = (d & 7) * 512 + (d >> 3);   // bijective (4096 % 8 == 0)
  const int ct = L & 7;
  const int pt = (L >> 3) & 31;
  const int b  = L >> 8;

  const int tid = threadIdx.x;
  const int lane = tid & 63, w = tid >> 6;
  const int lr = lane & 15, kg = lane >> 4;

  // ---- B staging addresses (same mapping as r2/r4, which passed) ----
  const char* ksbase = (const char*)ks + (size_t)(ct >> 1) * NKC * 16384 + (ct & 1) * 4096;
  const char* bsrc[2];
  bsrc[0] = ksbase + tid * 16;          // hi half-chunk quarter
  bsrc[1] = ksbase + 8192 + tid * 16;   // lo

  // ---- A pointers: row = w*32 + fp*16 + lr, k elems = kc*32 + kg*8 + h*4 ----
  const char* xbase = (const char*)(x + ((size_t)b * PN + (size_t)pt * TP) * DD);
  const char* ap[2][2];
#pragma unroll
  for (int fp = 0; fp < 2; fp++)
#pragma unroll
    for (int h = 0; h < 2; h++)
      ap[fp][h] = xbase + (size_t)(w * 32 + fp * 16 + lr) * (DD * 4) + kg * 32 + h * 16;

  float4 abuf[3][2][2];   // [kc%3][fp][h] -- all indices compile-time (full unroll)

  auto issue = [&](int kc) {        // exactly 6 VM ops per call
    char* Bb = lds + (kc % 3) * 8192;
#pragma unroll
    for (int i = 0; i < 2; i++)
      gld16(bsrc[i] + kc * 16384, Bb + i * 4096 + tid * 16);
#pragma unroll
    for (int fp = 0; fp < 2; fp++)
#pragma unroll
      for (int h = 0; h < 2; h++)
        abuf[kc % 3][fp][h] = *(const float4*)(ap[fp][h] + kc * 128);
  };

  issue(0);
  issue(1);
  MEMFENCE();
  __builtin_amdgcn_s_waitcnt(WAITCNT_VM6);   // chunk-0 group landed; chunk-1 in flight
  __builtin_amdgcn_s_barrier();              // everyone's chunk-0 B staged
  MEMFENCE();

  f32x4 acc[2][4];
#pragma unroll
  for (int i = 0; i < 2; i++)
#pragma unroll
    for (int j = 0; j < 4; j++) acc[i][j] = (f32x4)0.f;

#pragma unroll
  for (int kc = 0; kc < NKC; kc++) {
    if (kc + 2 < NKC) issue(kc + 2);         // 2-deep: in flight across 2 computes

    bf16x8 Ah[2], Al[2];
#pragma unroll
    for (int fp = 0; fp < 2; fp++) {
      uint2 h0, l0, h1, l1;
      split4(abuf[kc % 3][fp][0], h0, l0);
      split4(abuf[kc % 3][fp][1], h1, l1);
      uint4 hh = make_uint4(h0.x, h0.y, h1.x, h1.y);
      uint4 ll = make_uint4(l0.x, l0.y, l1.x, l1.y);
      Ah[fp] = *(bf16x8*)&hh;
      Al[fp] = *(bf16x8*)&ll;
    }
    const char* Bb = lds + (kc % 3) * 8192;
#pragma unroll
    for (int fc = 0; fc < 4; fc++) {
      bf16x8 Bh = *(const bf16x8*)(Bb + fc * 1024 + lane * 16);
      bf16x8 Bl = *(const bf16x8*)(Bb + 4096 + fc * 1024 + lane * 16);
#pragma unroll
      for (int fp = 0; fp < 2; fp++) {
        acc[fp][fc] = __builtin_amdgcn_mfma_f32_16x16x32_bf16(Ah[fp], Bh, acc[fp][fc], 0, 0, 0);
        acc[fp][fc] = __builtin_amdgcn_mfma_f32_16x16x32_bf16(Ah[fp], Bl, acc[fp][fc], 0, 0, 0);
        acc[fp][fc] = __builtin_amdgcn_mfma_f32_16x16x32_bf16(Al[fp], Bh, acc[fp][fc], 0, 0, 0);
      }
    }
    MEMFENCE();
    // Before the barrier: require next chunk's group (issued last iter) landed,
    // but keep the newest group (issued this iter) in flight across the barrier.
    if (kc + 2 < NKC) {
      __builtin_amdgcn_s_waitcnt(WAITCNT_VM6);   // issue(kc+1) landed
    } else if (kc + 1 < NKC) {
      __builtin_amdgcn_s_waitcnt(WAITCNT_VM0);   // tail: only issue(7) outstanding
    }
    __builtin_amdgcn_s_barrier();            // WAR fence + B producer-consumer
    MEMFENCE();
  }
  // loop-end barrier doubles as pre-scratch sync (all chunk-7 LDS reads retired)

  // relu + per-lane top2 per column (C layout: col=lane&15, row=(lane>>4)*4+reg)
  float4* scratch = (float4*)lds;            // [slot 0..15][col 0..63] = 16 KB
  const int slot = w * 4 + kg;
#pragma unroll
  for (int fc = 0; fc < 4; fc++) {
    Top2 t; t.v1 = -1.f; t.v2 = -1.f; t.i1 = 0x7fffffff; t.i2 = 0x7fffffff;
#pragma unroll
    for (int fp = 0; fp < 2; fp++)
#pragma unroll
      for (int r = 0; r < 4; r++) {
        float v = acc[fp][fc][r]; v = v > 0.f ? v : 0.f;
        t2_insert(t, v, w * 32 + fp * 16 + kg * 4 + r);
      }
    scratch[slot * TC + fc * 16 + lr] =
        make_float4(t.v1, __int_as_float(t.i1), t.v2, __int_as_float(t.i2));
  }
  __syncthreads();

  if (tid < TC) {
    Top2 t; t.v1 = -1.f; t.v2 = -1.f; t.i1 = 0x7fffffff; t.i2 = 0x7fffffff;
#pragma unroll
    for (int s = 0; s < 16; s++) {
      float4 e = scratch[s * TC + tid];
      t2_insert(t, e.x, __float_as_int(e.y));
      t2_insert(t, e.z, __float_as_int(e.w));
    }
    int c = ct * TC + tid;
    size_t o = ((size_t)b * CC + c) * NPT + pt;
    uint32_t p1 = (uint32_t)(pt * TP + t.i1);
    uint32_t p2 = (uint32_t)(pt * TP + t.i2);
    pv2[o] = make_float2(t.v1, t.v2);
    pix[o] = (p1 << 16) | (p2 & 0xffffu);
  }
}

// ---------------------------------------------------------------------------
// Per-(b,c): merge 32 tile top-2s; eps-guarded winner; exact fp32 rescue of
// near-ties. Writes winner[b][c] only.
// ---------------------------------------------------------------------------
__global__ __launch_bounds__(64) void reduce_winner_kernel(
    const float2* __restrict__ pv2, const uint32_t* __restrict__ pix,
    const float* __restrict__ x, const float* __restrict__ kern,
    int* __restrict__ winner) {
  const int c = blockIdx.x, b = blockIdx.y;
  const int l = threadIdx.x;

  Top2 t; t.v1 = -1.f; t.v2 = -1.f; t.i1 = 0x7fffffff; t.i2 = 0x7fffffff;
  if (l < NPT) {
    size_t o = ((size_t)b * CC + c) * NPT + l;
    float2 v = pv2[o]; uint32_t ii = pix[o];
    t.v1 = v.x; t.v2 = v.y; t.i1 = (int)(ii >> 16); t.i2 = (int)(ii & 0xffffu);
  }
#pragma unroll
  for (int m = 1; m < 64; m <<= 1) {
    float uv1 = __shfl_xor(t.v1, m, 64);
    int   ui1 = __shfl_xor(t.i1, m, 64);
    float uv2 = __shfl_xor(t.v2, m, 64);
    int   ui2 = __shfl_xor(t.i2, m, 64);
    t2_insert(t, uv1, ui1);
    t2_insert(t, uv2, ui2);
  }

  int win = t.i1;
  if (t.v1 - t.v2 <= 1e-4f * t.v1 + 1e-5f) {   // rare near-tie: exact fp32
    const float4* x1 = (const float4*)(x + ((size_t)b * PN + t.i1) * DD);
    const float4* x2 = (const float4*)(x + ((size_t)b * PN + t.i2) * DD);
    const float4* kc = (const float4*)(kern + (size_t)c * DD);
    float4 a1 = x1[l], a2 = x2[l], k4 = kc[l];
    float s1 = a1.x * k4.x + a1.y * k4.y + a1.z * k4.z + a1.w * k4.w;
    float s2 = a2.x * k4.x + a2.y * k4.y + a2.z * k4.z + a2.w * k4.w;
#pragma unroll
    for (int m = 1; m < 64; m <<= 1) {
      s1 += __shfl_xor(s1, m, 64);
      s2 += __shfl_xor(s2, m, 64);
    }
    s1 = fmaxf(s1, 0.f); s2 = fmaxf(s2, 0.f);
    if (s2 > s1 || (s2 == s1 && t.i2 < t.i1)) win = t.i2;
  }
  if (l == 0) winner[(size_t)b * CC + c] = win;
}

// ---------------------------------------------------------------------------
// 4 positions per block (4 waves); winner row staged in LDS once per block.
// Each wave ballots matching channels, sums kernel rows, writes its row.
// Full coverage -> no memset, no atomics.
// ---------------------------------------------------------------------------
__global__ __launch_bounds__(256) void write_out_kernel(
    const int* __restrict__ winner, const float* __restrict__ kern,
    float4* __restrict__ out) {
  __shared__ __align__(16) int wrow[CC];
  const int b = blockIdx.y;
  const int tid = threadIdx.x, lane = tid & 63, w = tid >> 6;
  const int p = blockIdx.x * 4 + w;

  *(int2*)&wrow[tid * 2] = *(const int2*)&winner[(size_t)b * CC + tid * 2];
  __syncthreads();

  int4 w0 = *(const int4*)&wrow[lane * 8];
  int4 w1 = *(const int4*)&wrow[lane * 8 + 4];
  int wv[8] = {w0.x, w0.y, w0.z, w0.w, w1.x, w1.y, w1.z, w1.w};

  float4 acc = make_float4(0.f, 0.f, 0.f, 0.f);
#pragma unroll
  for (int j = 0; j < 8; j++) {
    unsigned long long m = __ballot(wv[j] == p);
    while (m) {
      int bit = __ffsll((long long)m) - 1; m &= m - 1;
      int c = bit * 8 + j;                      // wave-uniform
      float4 kv = ((const float4*)(kern + (size_t)c * DD))[lane];
      acc.x += kv.x; acc.y += kv.y; acc.z += kv.z; acc.w += kv.w;
    }
  }
  out[((size_t)b * PN + p) * 64 + lane] = acc;
}

// ---------------------------------------------------------------------------
extern "C" void kernel_launch(void* const* d_in, const int* in_sizes, int n_in,
                              void* d_out, int out_size, void* d_ws, size_t ws_size,
                              hipStream_t stream) {
  const float* x    = (const float*)d_in[0];   // (16,4096,256)
  const float* kern = (const float*)d_in[1];   // (512,256)
  float* out = (float*)d_out;

  // ws: pv2 2 MB | pix 1 MB | ks 512 KB | winner 32 KB
  char* ws = (char*)d_ws;
  float2*   pv2 = (float2*)ws;
  uint32_t* pix = (uint32_t*)(ws + (size_t)BSZ * CC * NPT * sizeof(float2));
  uint32_t* ks  = (uint32_t*)(ws + 3u * 1024 * 1024);
  int*      win = (int*)(ws + 3u * 1024 * 1024 + 512u * 1024);

  convert_k_kernel<<<dim3(NKC, CC / 128), 256, 0, stream>>>(kern, ks);

  score_kernel<<<dim3(NCT * NPT * BSZ), 256, 0, stream>>>(x, ks, pv2, pix);

  reduce_winner_kernel<<<dim3(CC, BSZ), 64, 0, stream>>>(pv2, pix, x, kern, win);

  write_out_kernel<<<dim3(PN / 4, BSZ), 256, 0, stream>>>(win, kern, (float4*)out);
}